// Round 3
// baseline (657.955 us; speedup 1.0000x reference)
//
#include <hip/hip_runtime.h>

// Problem constants (fixed by setup_inputs)
#define BQ   16
#define HH   512
#define WW   512
#define CC   3
#define PSZ  16
#define STR  8
#define PYN  63
#define PXN  63
#define NPATCH (BQ * PYN * PXN)   // 63504
#define PPC  768                  // elements per patch (16*16*3)
#define KGEMM 1536                // MFMA K extent (p1 | p2); rem handled in epilogue
#define HID  512
#define MT   32                   // patches (M rows) per block
#define NTH  512                  // 8 waves: 2 M-waves x 4 N-waves
#define FSTR 1544                 // feat row stride (ushort) -> 3088 B, 2-way bank alias (free)
#define KSTEPS 48                 // 1536 / 32

typedef __attribute__((ext_vector_type(8))) short  short8;
typedef __attribute__((ext_vector_type(4))) float  f32x4;

__device__ __forceinline__ ushort f2bf(float f) {
    unsigned u = __float_as_uint(f);
    u = (u + 0x7fffu + ((u >> 16) & 1u)) >> 16;   // RNE
    return (ushort)u;
}
__device__ __forceinline__ float bf2f(ushort h) {
    return __uint_as_float(((unsigned)h) << 16);
}

// Pack w1[0:1536][0:512] -> bf16 in B-fragment order: w1p[((k>>3)*512 + n)*8 + (k&7)]
__global__ void pack_w1_kernel(const float* __restrict__ w1, ushort* __restrict__ w1p) {
    int e = blockIdx.x * 256 + threadIdx.x;   // 0 .. 1536*512-1
    int k = e >> 9;
    int n = e & 511;
    w1p[((((k >> 3) << 9) + n) << 3) + (k & 7)] = f2bf(w1[e]);
}

__global__ __launch_bounds__(NTH, 2)
void lfe_mfma_kernel(const float* __restrict__ img1,
                     const float* __restrict__ img2,
                     const float* __restrict__ prior,
                     const float* __restrict__ w1,
                     const float* __restrict__ b1,
                     const float* __restrict__ w2,
                     const float* __restrict__ b2,
                     const ushort* __restrict__ w1p,
                     float* __restrict__ out)
{
    __shared__ ushort feat[MT][FSTR];   // [p1(768) | p2(768) | pad]
    __shared__ float  srem[MT][2];
    __shared__ int    sip[MT][2];
    __shared__ float  red[4][MT][2];
    __shared__ float  sflow[MT][2];

    const int t  = threadIdx.x;
    const int n0 = blockIdx.x * MT;

    // ---- Phase 0: int prior + remainder ----
    if (t < MT) {
        int n = min(n0 + t, NPATCH - 1);
        float py = prior[(size_t)n * 2 + 0];
        float px = prior[(size_t)n * 2 + 1];
        int ipy = (int)rintf(py);    // round-half-even == jnp.round
        int ipx = (int)rintf(px);
        sip[t][0] = ipy; sip[t][1] = ipx;
        srem[t][0] = py - (float)ipy;
        srem[t][1] = px - (float)ipx;
    }
    __syncthreads();

    // ---- Phase 1: stage patches (bf16) into LDS. One (patch,row) per thread. ----
    {
        int pi = t >> 4, r = t & 15;
        int n  = min(n0 + pi, NPATCH - 1);
        int b  = n / (PYN * PXN);
        int rr = n % (PYN * PXN);
        int py = rr / PXN, px = rr % PXN;
        int by = py * STR, bx = px * STR;
        int sy = min(max(by + sip[pi][0], 0), HH - PSZ);
        int sx = min(max(bx + sip[pi][1], 0), WW - PSZ);
        const float* r1 = img1 + (((size_t)b * HH + by + r) * WW + bx) * CC;
        const float* r2 = img2 + (((size_t)b * HH + sy + r) * WW + sx) * CC;
        #pragma unroll
        for (int j = 0; j < 48; ++j) feat[pi][r * 48 + j] = f2bf(r1[j]);
        #pragma unroll
        for (int j = 0; j < 48; ++j) feat[pi][PPC + r * 48 + j] = f2bf(r2[j]);
    }
    __syncthreads();

    // ---- Phase 2: MFMA GEMM  acc = feat(32x1536) @ w1(1536x512), per-wave 16x128 ----
    const int wid  = t >> 6;          // 0..7
    const int wm   = wid >> 2;        // 0..1  (M tile)
    const int wn   = wid & 3;         // 0..3  (128-col slice)
    const int lane = t & 63;
    const int cn   = lane & 15;       // A row / B col / C col
    const int g    = lane >> 4;       // k-group / C row group

    f32x4 acc[8];
    #pragma unroll
    for (int i = 0; i < 8; ++i) acc[i] = f32x4{0.f, 0.f, 0.f, 0.f};

    const short8* bbase = reinterpret_cast<const short8*>(w1p) + (g << 9) + (wn << 7) + cn;
    const ushort* arow  = &feat[(wm << 4) + cn][0];

    #pragma unroll 2
    for (int step = 0; step < KSTEPS; ++step) {
        short8 a = *reinterpret_cast<const short8*>(arow + step * 32 + (g << 3));
        const short8* bs = bbase + step * 2048;
        #pragma unroll
        for (int nt = 0; nt < 8; ++nt) {
            short8 bfrag = bs[nt << 4];
            acc[nt] = __builtin_amdgcn_mfma_f32_16x16x32_bf16(a, bfrag, acc[nt], 0, 0, 0);
        }
    }

    // ---- Phase 3: epilogue — rem features + b1, ReLU, fold w2, reduce ----
    float ps0[4] = {0.f, 0.f, 0.f, 0.f};
    float ps1[4] = {0.f, 0.f, 0.f, 0.f};
    #pragma unroll
    for (int nt = 0; nt < 8; ++nt) {
        int j = (wn << 7) + (nt << 4) + cn;
        float w1a = w1[(size_t)1536 * HID + j];
        float w1b = w1[(size_t)1537 * HID + j];
        float bb  = b1[j];
        float w20 = w2[(size_t)j * 2 + 0];
        float w21 = w2[(size_t)j * 2 + 1];
        #pragma unroll
        for (int reg = 0; reg < 4; ++reg) {
            int lm = (wm << 4) + (g << 2) + reg;    // C/D: row=(lane>>4)*4+reg
            float h = acc[nt][reg] + bb + srem[lm][0] * w1a + srem[lm][1] * w1b;
            h = fmaxf(h, 0.f);
            ps0[reg] = fmaf(h, w20, ps0[reg]);
            ps1[reg] = fmaf(h, w21, ps1[reg]);
        }
    }
    #pragma unroll
    for (int reg = 0; reg < 4; ++reg) {
        #pragma unroll
        for (int off = 1; off < 16; off <<= 1) {
            ps0[reg] += __shfl_xor(ps0[reg], off, 64);
            ps1[reg] += __shfl_xor(ps1[reg], off, 64);
        }
    }
    if (cn == 0) {
        #pragma unroll
        for (int reg = 0; reg < 4; ++reg) {
            int lm = (wm << 4) + (g << 2) + reg;
            red[wn][lm][0] = ps0[reg];
            red[wn][lm][1] = ps1[reg];
        }
    }
    __syncthreads();
    if (t < MT * 2) {
        int lm = t >> 1, c = t & 1;
        float v = red[0][lm][c] + red[1][lm][c] + red[2][lm][c] + red[3][lm][c] + b2[c];
        sflow[lm][c] = srem[lm][c] + v;   // remainder_flow
    }
    __syncthreads();

    // ---- Phase 4: bilinear warp loss (16 lanes per patch) ----
    {
        int pi = t >> 4, lt = t & 15;
        float rfy = sflow[pi][0], rfx = sflow[pi][1];
        const ushort* p1v = &feat[pi][0];
        const ushort* p2v = &feat[pi][PPC];
        float lsum = 0.f;
        #pragma unroll 4
        for (int m = 0; m < 48; ++m) {
            int e = lt + (m << 4);
            int c = e % 3;
            int q = e / 3;            // yi*16 + xj
            int xj = q & 15, yi = q >> 4;
            float y = (float)yi + rfy;
            float x = (float)xj + rfx;
            int y0 = min(max((int)floorf(y), 0), PSZ - 1);
            int x0 = min(max((int)floorf(x), 0), PSZ - 1);
            int y1 = min(y0 + 1, PSZ - 1);
            int x1 = min(x0 + 1, PSZ - 1);
            float wy = fminf(fmaxf(y - (float)y0, 0.f), 1.f);
            float wx = fminf(fmaxf(x - (float)x0, 0.f), 1.f);
            float v00 = bf2f(p2v[(y0 * PSZ + x0) * CC + c]);
            float v01 = bf2f(p2v[(y0 * PSZ + x1) * CC + c]);
            float v10 = bf2f(p2v[(y1 * PSZ + x0) * CC + c]);
            float v11 = bf2f(p2v[(y1 * PSZ + x1) * CC + c]);
            float warped = (1.f - wy) * ((1.f - wx) * v00 + wx * v01)
                         +        wy  * ((1.f - wx) * v10 + wx * v11);
            float d = warped - bf2f(p1v[e]);
            lsum = fmaf(d, d, lsum);
        }
        #pragma unroll
        for (int off = 1; off < 16; off <<= 1)
            lsum += __shfl_xor(lsum, off, 64);

        int n = n0 + pi;
        if (lt == 0 && n < NPATCH) {
            out[(size_t)n * 3 + 0] = (float)sip[pi][0] + rfy;
            out[(size_t)n * 3 + 1] = (float)sip[pi][1] + rfx;
            out[(size_t)n * 3 + 2] = lsum * (1.f / 768.f);
        }
    }
}

extern "C" void kernel_launch(void* const* d_in, const int* in_sizes, int n_in,
                              void* d_out, int out_size, void* d_ws, size_t ws_size,
                              hipStream_t stream) {
    const float* img1  = (const float*)d_in[0];
    const float* img2  = (const float*)d_in[1];
    const float* prior = (const float*)d_in[2];
    const float* w1    = (const float*)d_in[3];
    const float* b1    = (const float*)d_in[4];
    const float* w2    = (const float*)d_in[5];
    const float* b2    = (const float*)d_in[6];
    float* out = (float*)d_out;
    ushort* w1p = (ushort*)d_ws;            // 1536*512*2 B = 1.57 MB

    pack_w1_kernel<<<dim3((KGEMM * HID) / 256), dim3(256), 0, stream>>>(w1, w1p);

    dim3 grid((NPATCH + MT - 1) / MT);      // 1985 blocks
    dim3 block(NTH);
    lfe_mfma_kernel<<<grid, block, 0, stream>>>(img1, img2, prior, w1, b1, w2, b2, w1p, out);
}

// Round 6
// 495.960 us; speedup vs baseline: 1.3266x; 1.3266x over previous
//
#include <hip/hip_runtime.h>

// Problem constants (fixed by setup_inputs)
#define BQ   16
#define HH   512
#define WW   512
#define CC   3
#define PSZ  16
#define STR  8
#define PYN  63
#define PXN  63
#define NPATCH (BQ * PYN * PXN)   // 63504
#define PPC  768                  // elements per patch (16*16*3)
#define KGEMM 1536                // MFMA K extent (p1 | p2); rem in epilogue
#define HID  512
#define MT   32                   // patches (M rows) per block
#define NTH  512                  // 8 waves; each wave: 2 M-tiles x 64 N-cols
#define FSTR 1544                 // feat row stride (ushort) -> 3088 B (16B-aligned rows)
#define KSTEPS 48                 // 1536 / 32

typedef __attribute__((ext_vector_type(8))) short  short8;
typedef __attribute__((ext_vector_type(4))) float  f32x4;
typedef const __attribute__((address_space(1))) void* as1_t;
typedef __attribute__((address_space(3))) void*       as3_t;

__device__ __forceinline__ ushort f2bf(float f) {
    unsigned u = __float_as_uint(f);
    u = (u + 0x7fffu + ((u >> 16) & 1u)) >> 16;   // RNE
    return (ushort)u;
}
__device__ __forceinline__ float bf2f(ushort h) {
    return __uint_as_float(((unsigned)h) << 16);
}
__device__ __forceinline__ unsigned pk2(float a, float b) {
    return (unsigned)f2bf(a) | ((unsigned)f2bf(b) << 16);
}

// Pack w1[0:1536][0:512] -> bf16 B-fragment order: w1p[((k>>3)*512 + n)*8 + (k&7)]
// k-step slab s (K=32) = w1p[s*16384 .. s*16384+16384) ushorts, contiguous.
__global__ void pack_w1_kernel(const float* __restrict__ w1, ushort* __restrict__ w1p) {
    int e = blockIdx.x * 256 + threadIdx.x;   // 0 .. 1536*512-1
    int k = e >> 9;
    int n = e & 511;
    w1p[((((k >> 3) << 9) + n) << 3) + (k & 7)] = f2bf(w1[e]);
}

__global__ __launch_bounds__(NTH, 2)
void lfe_mfma_kernel(const float* __restrict__ img1,
                     const float* __restrict__ img2,
                     const float* __restrict__ prior,
                     const float* __restrict__ w1,
                     const float* __restrict__ b1,
                     const float* __restrict__ w2,
                     const float* __restrict__ b2,
                     const ushort* __restrict__ w1p,
                     float* __restrict__ out)
{
    __shared__ ushort feat[MT][FSTR];        // 98816 B : [p1(768) | p2(768) | pad]
    __shared__ ushort bslab[32 * HID];       // 32768 B : B k-step tile, frag order
    __shared__ float  red[8][MT][2];         // 2048 B
    __shared__ float  srem[MT][2];
    __shared__ float  sflow[MT][2];
    __shared__ int    sip[MT][2];
    __shared__ int    sbase1[MT];            // float-index base of p1 patch
    __shared__ int    sbase2[MT];            // float-index base of shifted p2 patch

    const int t  = threadIdx.x;
    const int n0 = blockIdx.x * MT;

    // ---- Phase 0: prior -> int/remainder + patch base offsets ----
    if (t < MT) {
        int n = min(n0 + t, NPATCH - 1);
        float py_ = prior[(size_t)n * 2 + 0];
        float px_ = prior[(size_t)n * 2 + 1];
        int ipy = (int)rintf(py_);   // RNE == jnp.round
        int ipx = (int)rintf(px_);
        sip[t][0] = ipy; sip[t][1] = ipx;
        srem[t][0] = py_ - (float)ipy;
        srem[t][1] = px_ - (float)ipx;
        int b  = n / (PYN * PXN);
        int r  = n % (PYN * PXN);
        int py = r / PXN, px = r % PXN;
        int by = py * STR, bx = px * STR;
        int sy = min(max(by + ipy, 0), HH - PSZ);
        int sx = min(max(bx + ipx, 0), WW - PSZ);
        sbase1[t] = ((b * HH + by) * WW + bx) * CC;
        sbase2[t] = ((b * HH + sy) * WW + sx) * CC;
    }
    __syncthreads();

    // ---- Phase 1: stage patches (bf16 pairs) into LDS, coalesced ----
    // 384 float-pairs per patch per image; 32*384/512 = 24 iters.
    #pragma unroll 4
    for (int i = 0; i < 24; ++i) {
        int ep = t + (i << 9);
        int pi = ep / 384;
        int q  = ep - pi * 384;          // pair index within patch
        int yi = q / 24;
        int jp = q - yi * 24;            // pair within row (48 floats/row)
        int go = yi * (WW * CC) + jp * 2;
        const float* g1 = img1 + sbase1[pi] + go;
        const float* g2 = img2 + sbase2[pi] + go;
        *(unsigned*)(&feat[pi][2 * q])       = pk2(g1[0], g1[1]);
        *(unsigned*)(&feat[pi][PPC + 2 * q]) = pk2(g2[0], g2[1]);
    }
    __syncthreads();

    // ---- Phase 2: MFMA GEMM, B staged per k-step in LDS (shared by all waves) ----
    const int wid  = t >> 6;             // 0..7 : N-slice (64 cols)
    const int lane = t & 63;
    const int cn   = lane & 15;
    const int g    = lane >> 4;

    // stage_b: 32KB slab, 4KB per wave, 4 x 16B per lane
    auto stage_b = [&](int step) {
        const char* gb = (const char*)w1p + ((size_t)step << 15) + ((t >> 6) << 12) + ((t & 63) << 4);
        char* lb = (char*)bslab + ((t >> 6) << 12);
        #pragma unroll
        for (int i = 0; i < 4; ++i)
            __builtin_amdgcn_global_load_lds((as1_t)(gb + (i << 10)), (as3_t)(lb + (i << 10)), 16, 0, 0);
    };

    f32x4 acc0[4], acc1[4];
    #pragma unroll
    for (int nt = 0; nt < 4; ++nt) { acc0[nt] = f32x4{0,0,0,0}; acc1[nt] = f32x4{0,0,0,0}; }

    const ushort* a0 = &feat[cn][0];
    const ushort* a1 = &feat[16 + cn][0];
    const int bo = (((g << 9) + (wid << 6) + cn) << 3);   // ushort idx of B frag (nt=0)

    stage_b(0);
    __syncthreads();   // drains vmcnt -> slab 0 ready

    for (int step = 0; step < KSTEPS; ++step) {
        short8 Af0 = *(const short8*)(a0 + step * 32 + (g << 3));
        short8 Af1 = *(const short8*)(a1 + step * 32 + (g << 3));
        short8 Bf[4];
        #pragma unroll
        for (int nt = 0; nt < 4; ++nt)
            Bf[nt] = *(const short8*)(&bslab[bo + (nt << 7)]);
        __syncthreads();                       // all waves done reading slab
        if (step + 1 < KSTEPS) stage_b(step + 1);
        #pragma unroll
        for (int nt = 0; nt < 4; ++nt) {
            acc0[nt] = __builtin_amdgcn_mfma_f32_16x16x32_bf16(Af0, Bf[nt], acc0[nt], 0, 0, 0);
            acc1[nt] = __builtin_amdgcn_mfma_f32_16x16x32_bf16(Af1, Bf[nt], acc1[nt], 0, 0, 0);
        }
        __syncthreads();                       // vmcnt drained -> next slab ready
    }

    // ---- Phase 3: epilogue — rem features + b1, ReLU, fold w2, reduce ----
    float ps00[4], ps01[4], ps10[4], ps11[4];  // [reg] for mt=0/1, c=0/1
    #pragma unroll
    for (int r = 0; r < 4; ++r) { ps00[r]=0.f; ps01[r]=0.f; ps10[r]=0.f; ps11[r]=0.f; }
    #pragma unroll
    for (int nt = 0; nt < 4; ++nt) {
        int j = (wid << 6) + (nt << 4) + cn;
        float w1a = w1[(size_t)1536 * HID + j];
        float w1b = w1[(size_t)1537 * HID + j];
        float bb  = b1[j];
        float w20 = w2[(size_t)j * 2 + 0];
        float w21 = w2[(size_t)j * 2 + 1];
        #pragma unroll
        for (int r = 0; r < 4; ++r) {
            int lm0 = (g << 2) + r;            // C/D: row=(lane>>4)*4+reg
            float h0 = acc0[nt][r] + bb + srem[lm0][0] * w1a + srem[lm0][1] * w1b;
            h0 = fmaxf(h0, 0.f);
            ps00[r] = fmaf(h0, w20, ps00[r]);
            ps01[r] = fmaf(h0, w21, ps01[r]);
            int lm1 = 16 + lm0;
            float h1 = acc1[nt][r] + bb + srem[lm1][0] * w1a + srem[lm1][1] * w1b;
            h1 = fmaxf(h1, 0.f);
            ps10[r] = fmaf(h1, w20, ps10[r]);
            ps11[r] = fmaf(h1, w21, ps11[r]);
        }
    }
    #pragma unroll
    for (int r = 0; r < 4; ++r) {
        #pragma unroll
        for (int off = 1; off < 16; off <<= 1) {
            ps00[r] += __shfl_xor(ps00[r], off, 64);
            ps01[r] += __shfl_xor(ps01[r], off, 64);
            ps10[r] += __shfl_xor(ps10[r], off, 64);
            ps11[r] += __shfl_xor(ps11[r], off, 64);
        }
    }
    if (cn == 0) {
        #pragma unroll
        for (int r = 0; r < 4; ++r) {
            int lm0 = (g << 2) + r;
            red[wid][lm0][0] = ps00[r];
            red[wid][lm0][1] = ps01[r];
            red[wid][16 + lm0][0] = ps10[r];
            red[wid][16 + lm0][1] = ps11[r];
        }
    }
    __syncthreads();
    if (t < MT * 2) {
        int lm = t >> 1, c = t & 1;
        float v = b2[c];
        #pragma unroll
        for (int w = 0; w < 8; ++w) v += red[w][lm][c];
        sflow[lm][c] = srem[lm][c] + v;   // remainder_flow
    }
    __syncthreads();

    // ---- Phase 4: bilinear warp loss, lane <-> xj (x-side hoisted) ----
    {
        const int pi = t >> 4, lt = t & 15;
        const float rfy = sflow[pi][0], rfx = sflow[pi][1];
        const ushort* p1v = &feat[pi][0];
        const ushort* p2v = &feat[pi][PPC];

        float x  = (float)lt + rfx;
        int   x0 = min(max((int)floorf(x), 0), PSZ - 1);
        int   x1 = min(x0 + 1, PSZ - 1);
        float wx = fminf(fmaxf(x - (float)x0, 0.f), 1.f);
        int   c0 = x0 * 3, c1 = x1 * 3;

        float lsum = 0.f;
        #pragma unroll 4
        for (int yi = 0; yi < PSZ; ++yi) {
            float y  = (float)yi + rfy;
            int   y0 = min(max((int)floorf(y), 0), PSZ - 1);
            int   y1 = min(y0 + 1, PSZ - 1);
            float wy = fminf(fmaxf(y - (float)y0, 0.f), 1.f);
            int r0 = y0 * 48, r1 = y1 * 48;
            int pe = yi * 48 + lt * 3;
            #pragma unroll
            for (int c = 0; c < 3; ++c) {
                float v00 = bf2f(p2v[r0 + c0 + c]);
                float v01 = bf2f(p2v[r0 + c1 + c]);
                float v10 = bf2f(p2v[r1 + c0 + c]);
                float v11 = bf2f(p2v[r1 + c1 + c]);
                float a = v00 + wx * (v01 - v00);
                float b = v10 + wx * (v11 - v10);
                float warped = a + wy * (b - a);
                float d = warped - bf2f(p1v[pe + c]);
                lsum = fmaf(d, d, lsum);
            }
        }
        #pragma unroll
        for (int off = 1; off < 16; off <<= 1)
            lsum += __shfl_xor(lsum, off, 64);

        int n = n0 + pi;
        if (lt == 0 && n < NPATCH) {
            out[(size_t)n * 3 + 0] = (float)sip[pi][0] + rfy;
            out[(size_t)n * 3 + 1] = (float)sip[pi][1] + rfx;
            out[(size_t)n * 3 + 2] = lsum * (1.f / 768.f);
        }
    }
}

extern "C" void kernel_launch(void* const* d_in, const int* in_sizes, int n_in,
                              void* d_out, int out_size, void* d_ws, size_t ws_size,
                              hipStream_t stream) {
    const float* img1  = (const float*)d_in[0];
    const float* img2  = (const float*)d_in[1];
    const float* prior = (const float*)d_in[2];
    const float* w1    = (const float*)d_in[3];
    const float* b1    = (const float*)d_in[4];
    const float* w2    = (const float*)d_in[5];
    const float* b2    = (const float*)d_in[6];
    float* out = (float*)d_out;
    ushort* w1p = (ushort*)d_ws;            // 1536*512*2 B = 1.57 MB

    pack_w1_kernel<<<dim3((KGEMM * HID) / 256), dim3(256), 0, stream>>>(w1, w1p);

    dim3 grid((NPATCH + MT - 1) / MT);      // 1985 blocks
    dim3 block(NTH);
    lfe_mfma_kernel<<<grid, block, 0, stream>>>(img1, img2, prior, w1, b1, w2, b2, w1p, out);
}